// Round 6
// baseline (111.366 us; speedup 1.0000x reference)
//
#include <hip/hip_runtime.h>

#define NUM_CHR 24
#define N_EMB   512
#define DIM     512
#define BATCH   1024

#define T_SAMP     16   // samples per group
#define GROUPS_CAP 6    // covers 96 samples/chrom (Binom(1024,1/24)=42.7+-6.4 -> +8 sigma)
#define NSPLIT_N   16   // n-dimension split (partials)
#define NCHUNK     (N_EMB / NSPLIT_N)   // 32 rows per block
#define DSPLIT     2    // dim split (disjoint, no partials)
#define DSLICE     (DIM / DSPLIT)       // 256 floats

// ---- workspace layout (bytes) ----
#define OFF_COUNTS 0u
#define OFF_LISTS  1024u                 // 24*1024 ints = 98304 B
#define OFF_W      99328u                // 1024*512 f32 = 2 MiB
#define OFF_P      2196480u              // NSPLIT_N * 2 MiB partials = 32 MiB
#define P_BYTES    ((size_t)BATCH * DIM * sizeof(float))

// ---------------- Kernel 1: RBF weights + chromosome bucketing ----------------
__global__ __launch_bounds__(256) void atac_weights_kernel(
    const int* __restrict__ chrom, const float* __restrict__ pos,
    const float* __restrict__ centers, const float* __restrict__ logvar,
    float* __restrict__ W, int* __restrict__ counts, int* __restrict__ lists) {
  const int b = blockIdx.x;
  const int tid = threadIdx.x;
  const int c = chrom[b];
  const float p = pos[b];
  const int n0 = tid;
  const int n1 = tid + 256;
  const float* cc = centers + (size_t)c * N_EMB;
  const float* lv = logvar + (size_t)c * N_EMB;

  const float d0 = p - cc[n0];
  const float d1 = p - cc[n1];
  const float w0 = expf(-(d0 * d0) / (2.0f * expf(lv[n0])));
  const float w1 = expf(-(d1 * d1) / (2.0f * expf(lv[n1])));

  float s = w0 + w1;
#pragma unroll
  for (int off = 32; off > 0; off >>= 1) s += __shfl_down(s, off);
  __shared__ float part[4];
  __shared__ float invtot;
  if ((tid & 63) == 0) part[tid >> 6] = s;
  __syncthreads();
  if (tid == 0) invtot = 1.0f / (part[0] + part[1] + part[2] + part[3]);
  __syncthreads();

  float* Wb = W + (size_t)b * N_EMB;
  const float it = invtot;
  Wb[n0] = w0 * it;
  Wb[n1] = w1 * it;

  if (tid == 0) {
    const int slot = atomicAdd(&counts[c], 1);
    lists[c * BATCH + slot] = b;
  }
}

// ---------------- Kernel 2: grouped weighted-sum, depth-4 pipeline ----------------
// Block (c, grp, z): z = zn + 16*zd. 16 samples, n-rows [zn*32, zn*32+32),
// dims [zd*256, zd*256+256). 256 threads = 4 waves; wave sg owns samples
// sg*4..sg*4+3; lane owns 4 dims. Per row: one float4 E load (coalesced
// 1KB/wave) + one broadcast ds_read_b128 of 4 weights + 16 FMA (~34 cyc).
// Depth-4 rotating prefetch (e0..e3). With ~2300 active blocks and
// __launch_bounds__(256,8) -> 8 waves/SIMD resident: prefetch coverage
// 8 x 4 x 34 ~ 1090 cyc >= HBM latency -> stall-free, VALU-bound.
// Partials over zn only (dims disjoint): P[zn][sample][dim], plain stores.
__global__ __launch_bounds__(256, 8) void atac_reduce_kernel(
    const float* __restrict__ E, const float* __restrict__ W,
    const int* __restrict__ counts, const int* __restrict__ lists,
    float* __restrict__ P) {
  const int c = blockIdx.x;
  const int grp = blockIdx.y;
  const int zn = blockIdx.z & (NSPLIT_N - 1);
  const int zd = blockIdx.z >> 4;
  const int cnt = counts[c];
  const int base = grp * T_SAMP;
  if (base >= cnt) return;
  const int m = min(T_SAMP, cnt - base);
  const int tid = threadIdx.x;
  const int lane = tid & 63;
  const int sg = tid >> 6;       // wave index = sample group (4 samples)
  const int sg4 = sg * 4;

  __shared__ int sidx[T_SAMP];
  __shared__ float wlT[NCHUNK][20];  // [row][sample(16) + pad(4)]

  if (tid < T_SAMP) sidx[tid] = (tid < m) ? lists[c * BATCH + base + tid] : -1;
  __syncthreads();

  const int nbase = zn * NCHUNK;
  const int dbase = zd * DSLICE;

  // fill weight slice: T_SAMP*NCHUNK = 512 = 2 x 256 (coalesced 128B/sample)
#pragma unroll
  for (int k = 0; k < 2; ++k) {
    const int idx = tid + k * 256;
    const int t = idx >> 5;          // sample 0..15
    const int j = idx & (NCHUNK - 1);
    const int s = sidx[t];
    wlT[j][t] = (s >= 0) ? W[(size_t)s * N_EMB + nbase + j] : 0.0f;
  }
  __syncthreads();

  float4 acc0 = make_float4(0.f, 0.f, 0.f, 0.f);
  float4 acc1 = acc0, acc2 = acc0, acc3 = acc0;

  const float* Eb = E + (size_t)c * (N_EMB * DIM) + (size_t)nbase * DIM + dbase + lane * 4;

  float4 e0 = *(const float4*)(Eb + 0 * DIM);
  float4 e1 = *(const float4*)(Eb + 1 * DIM);
  float4 e2 = *(const float4*)(Eb + 2 * DIM);
  float4 e3 = *(const float4*)(Eb + 3 * DIM);

#define FMA16(EV, WV)                         \
  acc0.x = fmaf(WV.x, EV.x, acc0.x);          \
  acc0.y = fmaf(WV.x, EV.y, acc0.y);          \
  acc0.z = fmaf(WV.x, EV.z, acc0.z);          \
  acc0.w = fmaf(WV.x, EV.w, acc0.w);          \
  acc1.x = fmaf(WV.y, EV.x, acc1.x);          \
  acc1.y = fmaf(WV.y, EV.y, acc1.y);          \
  acc1.z = fmaf(WV.y, EV.z, acc1.z);          \
  acc1.w = fmaf(WV.y, EV.w, acc1.w);          \
  acc2.x = fmaf(WV.z, EV.x, acc2.x);          \
  acc2.y = fmaf(WV.z, EV.y, acc2.y);          \
  acc2.z = fmaf(WV.z, EV.z, acc2.z);          \
  acc2.w = fmaf(WV.z, EV.w, acc2.w);          \
  acc3.x = fmaf(WV.w, EV.x, acc3.x);          \
  acc3.y = fmaf(WV.w, EV.y, acc3.y);          \
  acc3.z = fmaf(WV.w, EV.z, acc3.z);          \
  acc3.w = fmaf(WV.w, EV.w, acc3.w);

#pragma unroll 1
  for (int j = 0; j < NCHUNK; j += 4) {
    const bool more = (j + 4 < NCHUNK);
    const float* En = Eb + (size_t)(j + 4) * DIM;
    {
      const float4 wv = *(const float4*)&wlT[j + 0][sg4];
      FMA16(e0, wv)
      if (more) e0 = *(const float4*)(En + 0 * DIM);
    }
    {
      const float4 wv = *(const float4*)&wlT[j + 1][sg4];
      FMA16(e1, wv)
      if (more) e1 = *(const float4*)(En + 1 * DIM);
    }
    {
      const float4 wv = *(const float4*)&wlT[j + 2][sg4];
      FMA16(e2, wv)
      if (more) e2 = *(const float4*)(En + 2 * DIM);
    }
    {
      const float4 wv = *(const float4*)&wlT[j + 3][sg4];
      FMA16(e3, wv)
      if (more) e3 = *(const float4*)(En + 3 * DIM);
    }
  }
#undef FMA16

  float* Pz = P + (size_t)zn * (BATCH * DIM) + dbase + lane * 4;
  if (sg4 + 0 < m) *(float4*)(Pz + (size_t)sidx[sg4 + 0] * DIM) = acc0;
  if (sg4 + 1 < m) *(float4*)(Pz + (size_t)sidx[sg4 + 1] * DIM) = acc1;
  if (sg4 + 2 < m) *(float4*)(Pz + (size_t)sidx[sg4 + 2] * DIM) = acc2;
  if (sg4 + 3 < m) *(float4*)(Pz + (size_t)sidx[sg4 + 3] * DIM) = acc3;
}

// ---------------- Kernel 3: sum partials over zn ----------------
__global__ __launch_bounds__(256) void atac_final_reduce(
    const float* __restrict__ P, float* __restrict__ out) {
  const int i = blockIdx.x * 256 + threadIdx.x;  // float4 index
  const float4* p = (const float4*)P;
  float4 s = p[i];
#pragma unroll
  for (int zz = 1; zz < NSPLIT_N; ++zz) {
    const float4 v = p[(size_t)zz * (BATCH * DIM / 4) + i];
    s.x += v.x; s.y += v.y; s.z += v.z; s.w += v.w;
  }
  ((float4*)out)[i] = s;
}

// ---------------- Fallback: fully fused naive (tiny workspace) ----------------
__global__ __launch_bounds__(512) void atac_fused_naive(
    const int* __restrict__ chrom, const float* __restrict__ pos,
    const float* __restrict__ E, const float* __restrict__ centers,
    const float* __restrict__ logvar, float* __restrict__ out) {
  const int b = blockIdx.x;
  const int tid = threadIdx.x;
  const int c = chrom[b];
  const float p = pos[b];
  __shared__ float w[N_EMB];
  __shared__ float red[8];

  const float d = p - centers[(size_t)c * N_EMB + tid];
  const float wv = expf(-(d * d) / (2.0f * expf(logvar[(size_t)c * N_EMB + tid])));
  float s = wv;
#pragma unroll
  for (int off = 32; off > 0; off >>= 1) s += __shfl_down(s, off);
  if ((tid & 63) == 0) red[tid >> 6] = s;
  __syncthreads();
  if (tid == 0) {
    float tot = 0.f;
#pragma unroll
    for (int i = 0; i < 8; ++i) tot += red[i];
    red[0] = 1.0f / tot;
  }
  __syncthreads();
  w[tid] = wv * red[0];
  __syncthreads();

  float acc = 0.f;
  const float* Ec = E + (size_t)c * (N_EMB * DIM) + tid;
  for (int n = 0; n < N_EMB; ++n) acc = fmaf(w[n], Ec[(size_t)n * DIM], acc);
  out[(size_t)b * DIM + tid] = acc;
}

extern "C" void kernel_launch(void* const* d_in, const int* in_sizes, int n_in,
                              void* d_out, int out_size, void* d_ws, size_t ws_size,
                              hipStream_t stream) {
  const int* chrom = (const int*)d_in[0];
  const float* pos = (const float*)d_in[1];
  const float* E = (const float*)d_in[2];
  const float* centers = (const float*)d_in[3];
  const float* logvar = (const float*)d_in[4];
  float* out = (float*)d_out;
  char* ws = (char*)d_ws;

  if (ws_size < OFF_P + (size_t)NSPLIT_N * P_BYTES) {
    atac_fused_naive<<<BATCH, 512, 0, stream>>>(chrom, pos, E, centers, logvar, out);
    return;
  }

  int* counts = (int*)(ws + OFF_COUNTS);
  int* lists = (int*)(ws + OFF_LISTS);
  float* W = (float*)(ws + OFF_W);
  float* P = (float*)(ws + OFF_P);

  hipMemsetAsync(counts, 0, NUM_CHR * sizeof(int), stream);
  atac_weights_kernel<<<BATCH, 256, 0, stream>>>(chrom, pos, centers, logvar, W,
                                                 counts, lists);
  atac_reduce_kernel<<<dim3(NUM_CHR, GROUPS_CAP, NSPLIT_N * DSPLIT), 256, 0, stream>>>(
      E, W, counts, lists, P);
  atac_final_reduce<<<(BATCH * DIM / 4) / 256, 256, 0, stream>>>(P, out);
}

// Round 7
// 104.224 us; speedup vs baseline: 1.0685x; 1.0685x over previous
//
#include <hip/hip_runtime.h>

#define NUM_CHR 24
#define N_EMB   512
#define DIM     512
#define BATCH   1024

#define T_SAMP     16   // samples per group
#define GROUPS_CAP 6    // covers 96 samples/chrom (Binom(1024,1/24)=42.7+-6.4 -> +8 sigma)
#define NSPLIT_N   8    // n-dimension split (partials)
#define NCHUNK     (N_EMB / NSPLIT_N)   // 64 rows per block
#define DSPLIT     2    // dim split (disjoint, no partials)
#define DSLICE     (DIM / DSPLIT)       // 256 floats
#define RCHUNK     8    // rows staged to LDS per chunk
#define NCHUNKS    (NCHUNK / RCHUNK)    // 8

// ---- workspace layout (bytes) ----
#define OFF_COUNTS 0u
#define OFF_LISTS  1024u                 // 24*1024 ints = 98304 B
#define OFF_W      99328u                // 1024*512 f32 = 2 MiB
#define OFF_P      2196480u              // NSPLIT_N * 2 MiB partials = 16 MiB
#define P_BYTES    ((size_t)BATCH * DIM * sizeof(float))

// ---------------- Kernel 1: RBF weights + chromosome bucketing ----------------
__global__ __launch_bounds__(256) void atac_weights_kernel(
    const int* __restrict__ chrom, const float* __restrict__ pos,
    const float* __restrict__ centers, const float* __restrict__ logvar,
    float* __restrict__ W, int* __restrict__ counts, int* __restrict__ lists) {
  const int b = blockIdx.x;
  const int tid = threadIdx.x;
  const int c = chrom[b];
  const float p = pos[b];
  const int n0 = tid;
  const int n1 = tid + 256;
  const float* cc = centers + (size_t)c * N_EMB;
  const float* lv = logvar + (size_t)c * N_EMB;

  const float d0 = p - cc[n0];
  const float d1 = p - cc[n1];
  const float w0 = expf(-(d0 * d0) / (2.0f * expf(lv[n0])));
  const float w1 = expf(-(d1 * d1) / (2.0f * expf(lv[n1])));

  float s = w0 + w1;
#pragma unroll
  for (int off = 32; off > 0; off >>= 1) s += __shfl_down(s, off);
  __shared__ float part[4];
  __shared__ float invtot;
  if ((tid & 63) == 0) part[tid >> 6] = s;
  __syncthreads();
  if (tid == 0) invtot = 1.0f / (part[0] + part[1] + part[2] + part[3]);
  __syncthreads();

  float* Wb = W + (size_t)b * N_EMB;
  const float it = invtot;
  Wb[n0] = w0 * it;
  Wb[n1] = w1 * it;

  if (tid == 0) {
    const int slot = atomicAdd(&counts[c], 1);
    lists[c * BATCH + slot] = b;
  }
}

// ---------------- Kernel 2: grouped weighted-sum, LDS-staged via global_load_lds ----
// Block (c, grp, z): z = zn + 8*zd. 16 samples, n-rows [zn*64, zn*64+64),
// dims [zd*256, zd*256+256). 256 threads = 4 waves; wave sg owns samples
// sg*4..sg*4+3 and stages 2 rows/chunk via async DMA (global_load_lds, 16B/lane,
// linear LDS dest = wave-uniform base + lane*16). T3-minimal 2-phase schedule:
// issue next chunk's DMA -> compute current chunk from LDS -> one
// __syncthreads() per chunk (its implicit vmcnt(0) drains the DMA queue).
// Per row: ds_read_b128 e (contiguous, conflict-free) + broadcast ds_read_b128
// of 4 weights + 16 FMA. Partials P[zn][sample][dim], plain float4 stores.
__global__ __launch_bounds__(256) void atac_reduce_kernel(
    const float* __restrict__ E, const float* __restrict__ W,
    const int* __restrict__ counts, const int* __restrict__ lists,
    float* __restrict__ P) {
  const int c = blockIdx.x;
  const int grp = blockIdx.y;
  const int zn = blockIdx.z & (NSPLIT_N - 1);
  const int zd = blockIdx.z >> 3;
  const int cnt = counts[c];
  const int base = grp * T_SAMP;
  if (base >= cnt) return;
  const int m = min(T_SAMP, cnt - base);
  const int tid = threadIdx.x;
  const int lane = tid & 63;
  const int sg = tid >> 6;       // wave index = sample group (4 samples)
  const int sg4 = sg * 4;

  __shared__ int sidx[T_SAMP];
  __shared__ float wlT[NCHUNK][20];          // [row][sample(16) + pad(4)]
  __shared__ float ebuf[2][RCHUNK][DSLICE];  // double-buffered E chunk (2 x 8 KB)

  if (tid < T_SAMP) sidx[tid] = (tid < m) ? lists[c * BATCH + base + tid] : -1;
  __syncthreads();

  const int nbase = zn * NCHUNK;
  const int dbase = zd * DSLICE;

  // fill weight slice: T_SAMP*NCHUNK = 1024 = 4 x 256 (coalesced 256B/sample-row)
#pragma unroll
  for (int k = 0; k < 4; ++k) {
    const int idx = tid + k * 256;
    const int t = idx >> 6;          // sample 0..15
    const int j = idx & (NCHUNK - 1);
    const int s = sidx[t];
    wlT[j][t] = (s >= 0) ? W[(size_t)s * N_EMB + nbase + j] : 0.0f;
  }

  // wave-uniform E base for this block (per-lane +lane*4 added in STAGE)
  const float* Eb = E + (size_t)c * (N_EMB * DIM) + (size_t)nbase * DIM + dbase;

  // Wave sg stages rows sg*2, sg*2+1 of chunk CK into ebuf[NB]:
  // per-lane global src, wave-uniform LDS dest, lane*16B auto-offset.
#define STAGE(NB, CK)                                                          \
  {                                                                            \
    const float* g0 = Eb + (size_t)((CK) * RCHUNK + sg * 2) * DIM + lane * 4;  \
    __builtin_amdgcn_global_load_lds(                                          \
        (const __attribute__((address_space(1))) unsigned int*)g0,             \
        (__attribute__((address_space(3))) unsigned int*)&ebuf[NB][sg * 2][0], \
        16, 0, 0);                                                             \
    const float* g1 = g0 + DIM;                                                \
    __builtin_amdgcn_global_load_lds(                                          \
        (const __attribute__((address_space(1))) unsigned int*)g1,             \
        (__attribute__((address_space(3))) unsigned int*)&ebuf[NB][sg * 2 + 1][0], \
        16, 0, 0);                                                             \
  }

  float4 acc0 = make_float4(0.f, 0.f, 0.f, 0.f);
  float4 acc1 = acc0, acc2 = acc0, acc3 = acc0;

#define FMA16(EV, WV)                         \
  acc0.x = fmaf(WV.x, EV.x, acc0.x);          \
  acc0.y = fmaf(WV.x, EV.y, acc0.y);          \
  acc0.z = fmaf(WV.x, EV.z, acc0.z);          \
  acc0.w = fmaf(WV.x, EV.w, acc0.w);          \
  acc1.x = fmaf(WV.y, EV.x, acc1.x);          \
  acc1.y = fmaf(WV.y, EV.y, acc1.y);          \
  acc1.z = fmaf(WV.y, EV.z, acc1.z);          \
  acc1.w = fmaf(WV.y, EV.w, acc1.w);          \
  acc2.x = fmaf(WV.z, EV.x, acc2.x);          \
  acc2.y = fmaf(WV.z, EV.y, acc2.y);          \
  acc2.z = fmaf(WV.z, EV.z, acc2.z);          \
  acc2.w = fmaf(WV.z, EV.w, acc2.w);          \
  acc3.x = fmaf(WV.w, EV.x, acc3.x);          \
  acc3.y = fmaf(WV.w, EV.y, acc3.y);          \
  acc3.z = fmaf(WV.w, EV.z, acc3.z);          \
  acc3.w = fmaf(WV.w, EV.w, acc3.w);

  STAGE(0, 0);
  __syncthreads();  // drains DMA (implicit vmcnt(0)) + publishes wlT

  int cur = 0;
#pragma unroll 1
  for (int ck = 0; ck < NCHUNKS; ++ck) {
    if (ck + 1 < NCHUNKS) STAGE(cur ^ 1, ck + 1);   // async next-chunk DMA
#pragma unroll
    for (int r = 0; r < RCHUNK; ++r) {
      const float4 e = *(const float4*)&ebuf[cur][r][lane * 4];
      const float4 wv = *(const float4*)&wlT[ck * RCHUNK + r][sg4];
      FMA16(e, wv)
    }
    __syncthreads();  // next buf ready (vmcnt drain) + cur safe to overwrite
    cur ^= 1;
  }
#undef FMA16
#undef STAGE

  float* Pz = P + (size_t)zn * (BATCH * DIM) + dbase + lane * 4;
  if (sg4 + 0 < m) *(float4*)(Pz + (size_t)sidx[sg4 + 0] * DIM) = acc0;
  if (sg4 + 1 < m) *(float4*)(Pz + (size_t)sidx[sg4 + 1] * DIM) = acc1;
  if (sg4 + 2 < m) *(float4*)(Pz + (size_t)sidx[sg4 + 2] * DIM) = acc2;
  if (sg4 + 3 < m) *(float4*)(Pz + (size_t)sidx[sg4 + 3] * DIM) = acc3;
}

// ---------------- Kernel 3: sum partials over zn ----------------
__global__ __launch_bounds__(256) void atac_final_reduce(
    const float* __restrict__ P, float* __restrict__ out) {
  const int i = blockIdx.x * 256 + threadIdx.x;  // float4 index
  const float4* p = (const float4*)P;
  float4 s = p[i];
#pragma unroll
  for (int zz = 1; zz < NSPLIT_N; ++zz) {
    const float4 v = p[(size_t)zz * (BATCH * DIM / 4) + i];
    s.x += v.x; s.y += v.y; s.z += v.z; s.w += v.w;
  }
  ((float4*)out)[i] = s;
}

// ---------------- Fallback: fully fused naive (tiny workspace) ----------------
__global__ __launch_bounds__(512) void atac_fused_naive(
    const int* __restrict__ chrom, const float* __restrict__ pos,
    const float* __restrict__ E, const float* __restrict__ centers,
    const float* __restrict__ logvar, float* __restrict__ out) {
  const int b = blockIdx.x;
  const int tid = threadIdx.x;
  const int c = chrom[b];
  const float p = pos[b];
  __shared__ float w[N_EMB];
  __shared__ float red[8];

  const float d = p - centers[(size_t)c * N_EMB + tid];
  const float wv = expf(-(d * d) / (2.0f * expf(logvar[(size_t)c * N_EMB + tid])));
  float s = wv;
#pragma unroll
  for (int off = 32; off > 0; off >>= 1) s += __shfl_down(s, off);
  if ((tid & 63) == 0) red[tid >> 6] = s;
  __syncthreads();
  if (tid == 0) {
    float tot = 0.f;
#pragma unroll
    for (int i = 0; i < 8; ++i) tot += red[i];
    red[0] = 1.0f / tot;
  }
  __syncthreads();
  w[tid] = wv * red[0];
  __syncthreads();

  float acc = 0.f;
  const float* Ec = E + (size_t)c * (N_EMB * DIM) + tid;
  for (int n = 0; n < N_EMB; ++n) acc = fmaf(w[n], Ec[(size_t)n * DIM], acc);
  out[(size_t)b * DIM + tid] = acc;
}

extern "C" void kernel_launch(void* const* d_in, const int* in_sizes, int n_in,
                              void* d_out, int out_size, void* d_ws, size_t ws_size,
                              hipStream_t stream) {
  const int* chrom = (const int*)d_in[0];
  const float* pos = (const float*)d_in[1];
  const float* E = (const float*)d_in[2];
  const float* centers = (const float*)d_in[3];
  const float* logvar = (const float*)d_in[4];
  float* out = (float*)d_out;
  char* ws = (char*)d_ws;

  if (ws_size < OFF_P + (size_t)NSPLIT_N * P_BYTES) {
    atac_fused_naive<<<BATCH, 512, 0, stream>>>(chrom, pos, E, centers, logvar, out);
    return;
  }

  int* counts = (int*)(ws + OFF_COUNTS);
  int* lists = (int*)(ws + OFF_LISTS);
  float* W = (float*)(ws + OFF_W);
  float* P = (float*)(ws + OFF_P);

  hipMemsetAsync(counts, 0, NUM_CHR * sizeof(int), stream);
  atac_weights_kernel<<<BATCH, 256, 0, stream>>>(chrom, pos, centers, logvar, W,
                                                 counts, lists);
  atac_reduce_kernel<<<dim3(NUM_CHR, GROUPS_CAP, NSPLIT_N * DSPLIT), 256, 0, stream>>>(
      E, W, counts, lists, P);
  atac_final_reduce<<<(BATCH * DIM / 4) / 256, 256, 0, stream>>>(P, out);
}